// Round 1
// baseline (818.288 us; speedup 1.0000x reference)
//
#include <hip/hip_runtime.h>

static inline int cdiv(long long a, long long b) { return (int)((a + b - 1) / b); }

// ---------------------------------------------------------------------------
// deg[c] += 1 per edge (col = ei[E+e]); self-loop +1 folded into k_dis.
__global__ __launch_bounds__(256) void k_deg(const int* __restrict__ ei,
                                             float* __restrict__ deg, int E) {
    int e = blockIdx.x * 256 + threadIdx.x;
    if (e < E) atomicAdd(&deg[ei[E + e]], 1.0f);
}

// dis[i] = rsqrt(indeg + 1)  (self-loop guarantees deg >= 1)
__global__ __launch_bounds__(256) void k_dis(float* __restrict__ dis, int N) {
    int i = blockIdx.x * 256 + threadIdx.x;
    if (i < N) dis[i] = rsqrtf(dis[i] + 1.0f);
}

// norm[e] = dis[row]*dis[col]
__global__ __launch_bounds__(256) void k_norm(const int* __restrict__ ei,
                                              const float* __restrict__ dis,
                                              float* __restrict__ norm, int E) {
    int e = blockIdx.x * 256 + threadIdx.x;
    if (e < E) norm[e] = dis[ei[e]] * dis[ei[E + e]];
}

// ---------------------------------------------------------------------------
// Per node i: hw = x_i @ Wconv0 ; out_i = b_cls + relu(x_i@W_ego + b_ego) @ Wcls0
__global__ __launch_bounds__(256) void k_input(const float* __restrict__ x,
                                               const float* __restrict__ Wego,
                                               const float* __restrict__ bego,
                                               const float* __restrict__ Wconv0,
                                               const float* __restrict__ Wcls0,
                                               const float* __restrict__ bcls,
                                               float* __restrict__ hw,
                                               float* __restrict__ out, int N) {
    __shared__ float sWe[64 * 64];
    __shared__ float sWc[64 * 64];
    __shared__ float sWcls[64 * 40];
    __shared__ float sbe[64];
    __shared__ float sbc[40];
    for (int t = threadIdx.x; t < 64 * 64; t += 256) { sWe[t] = Wego[t]; sWc[t] = Wconv0[t]; }
    for (int t = threadIdx.x; t < 64 * 40; t += 256) sWcls[t] = Wcls0[t];
    if (threadIdx.x < 64) sbe[threadIdx.x] = bego[threadIdx.x];
    if (threadIdx.x < 40) sbc[threadIdx.x] = bcls[threadIdx.x];
    __syncthreads();

    int i = blockIdx.x * 256 + threadIdx.x;
    if (i >= N) return;

    float xr[64];
    const float4* xp = (const float4*)(x + (size_t)i * 64);
#pragma unroll
    for (int d4 = 0; d4 < 16; ++d4) {
        float4 v = xp[d4];
        xr[d4 * 4 + 0] = v.x; xr[d4 * 4 + 1] = v.y;
        xr[d4 * 4 + 2] = v.z; xr[d4 * 4 + 3] = v.w;
    }

    // hw = x @ Wconv0   (broadcast LDS reads of W, x in regs)
    float4* hwp = (float4*)(hw + (size_t)i * 64);
    for (int c4 = 0; c4 < 16; ++c4) {
        float4 acc = {0.f, 0.f, 0.f, 0.f};
#pragma unroll
        for (int d = 0; d < 64; ++d) {
            float xd = xr[d];
            const float4 w = *(const float4*)&sWc[d * 64 + c4 * 4];
            acc.x += xd * w.x; acc.y += xd * w.y;
            acc.z += xd * w.z; acc.w += xd * w.w;
        }
        hwp[c4] = acc;
    }

    // out = b_cls + relu(x@Wego + b_ego) @ Wcls0  (P0 stays in a scalar)
    float oacc[40];
#pragma unroll
    for (int j = 0; j < 40; ++j) oacc[j] = sbc[j];
    for (int c = 0; c < 64; ++c) {
        float acc = sbe[c];
#pragma unroll
        for (int d = 0; d < 64; ++d) acc += xr[d] * sWe[d * 64 + c];
        acc = fmaxf(acc, 0.0f);
#pragma unroll
        for (int j = 0; j < 40; ++j) oacc[j] += acc * sWcls[c * 40 + j];
    }
    float* op = out + (size_t)i * 40;
#pragma unroll
    for (int j = 0; j < 40; ++j) op[j] = oacc[j];
}

// ---------------------------------------------------------------------------
// Edge-parallel scatter: 64 lanes per edge, one feature each.
__global__ __launch_bounds__(256) void k_scatter(const int* __restrict__ ei,
                                                 const float* __restrict__ norm,
                                                 const float* __restrict__ hw,
                                                 float* __restrict__ agg, int E) {
    long long idx = (long long)blockIdx.x * 256 + threadIdx.x;
    int e = (int)(idx >> 6);
    int f = (int)(idx & 63);
    if (e >= E) return;
    int r = ei[e];
    int c = ei[E + e];
    float v = norm[e] * hw[(size_t)r * 64 + f];
    atomicAdd(&agg[(size_t)c * 64 + f], v);
}

// ---------------------------------------------------------------------------
// Per node: h = relu(agg + dis^2*hw_self + b); out += h@WclsPart;
// if !LAST: hw <- h@Wnext (next hop's transformed features), agg row <- 0.
template <bool LAST>
__global__ __launch_bounds__(256) void k_post(const float* __restrict__ dis,
                                              const float* __restrict__ bconv,
                                              const float* __restrict__ Wnext,
                                              const float* __restrict__ WclsPart,
                                              float* __restrict__ hw,
                                              float* __restrict__ agg,
                                              float* __restrict__ out, int N) {
    __shared__ float sWn[64 * 64];
    __shared__ float sWc[64 * 40];
    __shared__ float sb[64];
    if (!LAST)
        for (int t = threadIdx.x; t < 64 * 64; t += 256) sWn[t] = Wnext[t];
    for (int t = threadIdx.x; t < 64 * 40; t += 256) sWc[t] = WclsPart[t];
    if (threadIdx.x < 64) sb[threadIdx.x] = bconv[threadIdx.x];
    __syncthreads();

    int i = blockIdx.x * 256 + threadIdx.x;
    if (i >= N) return;

    float hr[64];
    float4* aggp = (float4*)(agg + (size_t)i * 64);
    float4* hwp = (float4*)(hw + (size_t)i * 64);
    float ds2 = dis[i];
    ds2 *= ds2;
#pragma unroll
    for (int c4 = 0; c4 < 16; ++c4) {
        float4 a = aggp[c4];
        float4 s = hwp[c4];
        hr[c4 * 4 + 0] = fmaxf(a.x + ds2 * s.x + sb[c4 * 4 + 0], 0.f);
        hr[c4 * 4 + 1] = fmaxf(a.y + ds2 * s.y + sb[c4 * 4 + 1], 0.f);
        hr[c4 * 4 + 2] = fmaxf(a.z + ds2 * s.z + sb[c4 * 4 + 2], 0.f);
        hr[c4 * 4 + 3] = fmaxf(a.w + ds2 * s.w + sb[c4 * 4 + 3], 0.f);
    }

    // out += h @ WclsPart
    float oacc[40];
    float* op = out + (size_t)i * 40;
#pragma unroll
    for (int j = 0; j < 40; ++j) oacc[j] = op[j];
    for (int c = 0; c < 64; ++c) {
        float hc = hr[c];
#pragma unroll
        for (int j = 0; j < 40; ++j) oacc[j] += hc * sWc[c * 40 + j];
    }
#pragma unroll
    for (int j = 0; j < 40; ++j) op[j] = oacc[j];

    if (!LAST) {
        for (int c4 = 0; c4 < 16; ++c4) {
            float4 acc = {0.f, 0.f, 0.f, 0.f};
#pragma unroll
            for (int d = 0; d < 64; ++d) {
                float hd = hr[d];
                const float4 w = *(const float4*)&sWn[d * 64 + c4 * 4];
                acc.x += hd * w.x; acc.y += hd * w.y;
                acc.z += hd * w.z; acc.w += hd * w.w;
            }
            hwp[c4] = acc;                          // next hop's transformed feats
            aggp[c4] = make_float4(0.f, 0.f, 0.f, 0.f);  // re-zero for next scatter
        }
    }
}

// ---------------------------------------------------------------------------
extern "C" void kernel_launch(void* const* d_in, const int* in_sizes, int n_in,
                              void* d_out, int out_size, void* d_ws, size_t ws_size,
                              hipStream_t stream) {
    const float* x     = (const float*)d_in[0];
    const int*   ei    = (const int*)d_in[1];   // [2,E] int32
    const float* Wego  = (const float*)d_in[2]; // [64,64]
    const float* bego  = (const float*)d_in[3]; // [64]
    const float* Wconv = (const float*)d_in[4]; // [2,64,64]
    const float* bconv = (const float*)d_in[5]; // [2,64]
    const float* Wcls  = (const float*)d_in[6]; // [192,40]
    const float* bcls  = (const float*)d_in[7]; // [40]
    float* out = (float*)d_out;

    const int N = in_sizes[0] / 64;
    const int E = in_sizes[1] / 2;

    // workspace layout (floats): dis[N] | norm[E] | hw[N*64] | agg[N*64]
    float* ws   = (float*)d_ws;
    float* dis  = ws;
    float* norm = dis + N;
    float* hw   = norm + E;
    float* agg  = hw + (size_t)N * 64;

    hipMemsetAsync(dis, 0, sizeof(float) * (size_t)N, stream);
    hipMemsetAsync(agg, 0, sizeof(float) * (size_t)N * 64, stream);

    k_deg<<<cdiv(E, 256), 256, 0, stream>>>(ei, dis, E);
    k_dis<<<cdiv(N, 256), 256, 0, stream>>>(dis, N);
    k_norm<<<cdiv(E, 256), 256, 0, stream>>>(ei, dis, norm, E);

    // hop 0 (ego) fused with hw1 = x @ Wconv[0]
    k_input<<<cdiv(N, 256), 256, 0, stream>>>(x, Wego, bego, Wconv, Wcls, bcls, hw, out, N);

    // hop 1
    k_scatter<<<cdiv((long long)E * 64, 256), 256, 0, stream>>>(ei, norm, hw, agg, E);
    k_post<false><<<cdiv(N, 256), 256, 0, stream>>>(dis, bconv, Wconv + 64 * 64,
                                                    Wcls + 64 * 40, hw, agg, out, N);
    // hop 2
    k_scatter<<<cdiv((long long)E * 64, 256), 256, 0, stream>>>(ei, norm, hw, agg, E);
    k_post<true><<<cdiv(N, 256), 256, 0, stream>>>(dis, bconv + 64, Wconv,
                                                   Wcls + 2 * 64 * 40, hw, agg, out, N);
}

// Round 2
// 586.879 us; speedup vs baseline: 1.3943x; 1.3943x over previous
//
#include <hip/hip_runtime.h>

static inline int cdiv(long long a, long long b) { return (int)((a + b - 1) / b); }

// ---------------------------------------------------------------------------
// Histogram of destination nodes: cnt[c]++ per edge.
__global__ __launch_bounds__(256) void k_hist(const int* __restrict__ ei,
                                              int* __restrict__ cnt, int E) {
    int e = blockIdx.x * 256 + threadIdx.x;
    if (e < E) atomicAdd(&cnt[ei[E + e]], 1);
}

// Per-block sums of cnt -> partial[b]
__global__ __launch_bounds__(256) void k_scan1(const int* __restrict__ cnt,
                                               int* __restrict__ partial, int N) {
    __shared__ int s[256];
    int i = blockIdx.x * 256 + threadIdx.x;
    s[threadIdx.x] = (i < N) ? cnt[i] : 0;
    __syncthreads();
    for (int st = 128; st > 0; st >>= 1) {
        if (threadIdx.x < st) s[threadIdx.x] += s[threadIdx.x + st];
        __syncthreads();
    }
    if (threadIdx.x == 0) partial[blockIdx.x] = s[0];
}

// Exclusive scan of nb (<=512) partials, single block of 512.
__global__ __launch_bounds__(512) void k_scan2(int* __restrict__ partial, int nb) {
    __shared__ int s[512];
    int t = threadIdx.x;
    int v = (t < nb) ? partial[t] : 0;
    s[t] = v;
    __syncthreads();
    for (int st = 1; st < 512; st <<= 1) {
        int add = (t >= st) ? s[t - st] : 0;
        __syncthreads();
        s[t] += add;
        __syncthreads();
    }
    if (t < nb) partial[t] = s[t] - v;  // exclusive
}

// indptr/cursor from block-local exclusive scan + block offset; dis = rsqrt(deg+1).
__global__ __launch_bounds__(256) void k_scan3(const int* __restrict__ cnt,
                                               const int* __restrict__ partial,
                                               int* __restrict__ indptr,
                                               int* __restrict__ cursor,
                                               float* __restrict__ dis, int N) {
    __shared__ int s[256];
    int i = blockIdx.x * 256 + threadIdx.x;
    int v = (i < N) ? cnt[i] : 0;
    s[threadIdx.x] = v;
    __syncthreads();
    for (int st = 1; st < 256; st <<= 1) {
        int add = (threadIdx.x >= st) ? s[threadIdx.x - st] : 0;
        __syncthreads();
        s[threadIdx.x] += add;
        __syncthreads();
    }
    if (i < N) {
        int excl = partial[blockIdx.x] + s[threadIdx.x] - v;
        indptr[i] = excl;
        cursor[i] = excl;
        dis[i] = rsqrtf((float)v + 1.0f);   // self-loop adds 1
        if (i == N - 1) indptr[N] = excl + v;  // == E
    }
}

// Fill CSR rows via atomic cursors (order within a segment is arbitrary).
__global__ __launch_bounds__(256) void k_reorder(const int* __restrict__ ei,
                                                 int* __restrict__ cursor,
                                                 int* __restrict__ rows, int E) {
    int e = blockIdx.x * 256 + threadIdx.x;
    if (e < E) {
        int r = ei[e];
        int c = ei[E + e];
        int pos = atomicAdd(&cursor[c], 1);
        rows[pos] = r;
    }
}

// ---------------------------------------------------------------------------
// Per node i: hws1 = dis[i] * (x_i @ Wconv0); out_i = b_cls + relu(x_i@W_ego+b_ego)@Wcls0
__global__ __launch_bounds__(256) void k_input(const float* __restrict__ x,
                                               const float* __restrict__ dis,
                                               const float* __restrict__ Wego,
                                               const float* __restrict__ bego,
                                               const float* __restrict__ Wconv0,
                                               const float* __restrict__ Wcls0,
                                               const float* __restrict__ bcls,
                                               float* __restrict__ hws,
                                               float* __restrict__ out, int N) {
    __shared__ float sWe[64 * 64];
    __shared__ float sWc[64 * 64];
    __shared__ float sWcls[64 * 40];
    __shared__ float sbe[64];
    __shared__ float sbc[40];
    for (int t = threadIdx.x; t < 64 * 64; t += 256) { sWe[t] = Wego[t]; sWc[t] = Wconv0[t]; }
    for (int t = threadIdx.x; t < 64 * 40; t += 256) sWcls[t] = Wcls0[t];
    if (threadIdx.x < 64) sbe[threadIdx.x] = bego[threadIdx.x];
    if (threadIdx.x < 40) sbc[threadIdx.x] = bcls[threadIdx.x];
    __syncthreads();

    int i = blockIdx.x * 256 + threadIdx.x;
    if (i >= N) return;

    float xr[64];
    const float4* xp = (const float4*)(x + (size_t)i * 64);
#pragma unroll
    for (int d4 = 0; d4 < 16; ++d4) {
        float4 v = xp[d4];
        xr[d4 * 4 + 0] = v.x; xr[d4 * 4 + 1] = v.y;
        xr[d4 * 4 + 2] = v.z; xr[d4 * 4 + 3] = v.w;
    }

    float dsi = dis[i];
    float4* hwp = (float4*)(hws + (size_t)i * 64);
    for (int c4 = 0; c4 < 16; ++c4) {
        float4 acc = {0.f, 0.f, 0.f, 0.f};
#pragma unroll
        for (int d = 0; d < 64; ++d) {
            float xd = xr[d];
            const float4 w = *(const float4*)&sWc[d * 64 + c4 * 4];
            acc.x += xd * w.x; acc.y += xd * w.y;
            acc.z += xd * w.z; acc.w += xd * w.w;
        }
        acc.x *= dsi; acc.y *= dsi; acc.z *= dsi; acc.w *= dsi;
        hwp[c4] = acc;
    }

    float oacc[40];
#pragma unroll
    for (int j = 0; j < 40; ++j) oacc[j] = sbc[j];
    for (int c = 0; c < 64; ++c) {
        float acc = sbe[c];
#pragma unroll
        for (int d = 0; d < 64; ++d) acc += xr[d] * sWe[d * 64 + c];
        acc = fmaxf(acc, 0.0f);
#pragma unroll
        for (int j = 0; j < 40; ++j) oacc[j] += acc * sWcls[c * 40 + j];
    }
    float* op = out + (size_t)i * 40;
#pragma unroll
    for (int j = 0; j < 40; ++j) op[j] = oacc[j];
}

// ---------------------------------------------------------------------------
// Fused hop: one wave per node (8 nodes / 512-thread block), lane f = feature.
//   acc_f = hws_in[i][f] (self) + sum over incoming edges hws_in[r][f]
//   h_f   = relu(dis[i]*acc_f + b[f])
//   out[i] += h @ WclsPart ; if !LAST: hws_out[i] = dis[i]*(h @ Wnext)
template <bool LAST>
__global__ __launch_bounds__(512) void k_hop(const int* __restrict__ indptr,
                                             const int* __restrict__ rows,
                                             const float* __restrict__ dis,
                                             const float* __restrict__ bconv,
                                             const float* __restrict__ Wnext,
                                             const float* __restrict__ WclsPart,
                                             const float* __restrict__ hws_in,
                                             float* __restrict__ hws_out,
                                             float* __restrict__ out, int N) {
    __shared__ float sWn[64 * 64];
    __shared__ float sWc[64 * 40];
    __shared__ float sb[64];
    __shared__ float sh[8][64];
    if (!LAST)
        for (int t = threadIdx.x; t < 64 * 64; t += 512) sWn[t] = Wnext[t];
    for (int t = threadIdx.x; t < 64 * 40; t += 512) sWc[t] = WclsPart[t];
    if (threadIdx.x < 64) sb[threadIdx.x] = bconv[threadIdx.x];
    __syncthreads();

    const int w = threadIdx.x >> 6;
    const int f = threadIdx.x & 63;
    const int i = blockIdx.x * 8 + w;
    const bool alive = (i < N);

    float h = 0.0f;
    float dsi = 0.0f;
    if (alive) {
        dsi = dis[i];
        float acc = hws_in[(size_t)i * 64 + f];   // self-loop term
        int p0 = indptr[i], p1 = indptr[i + 1];
        for (int p = p0; p < p1; ++p) {
            int r = rows[p];                       // uniform across wave
            acc += hws_in[(size_t)r * 64 + f];    // 256B coalesced gather
        }
        h = fmaxf(fmaf(dsi, acc, sb[f]), 0.0f);
    }
    sh[w][f] = h;
    __syncthreads();

    if (!LAST) {
        float a = 0.0f;
#pragma unroll
        for (int d = 0; d < 64; ++d) a += sh[w][d] * sWn[d * 64 + f];
        if (alive) hws_out[(size_t)i * 64 + f] = dsi * a;
    }
    if (f < 40) {
        float a = 0.0f;
#pragma unroll
        for (int d = 0; d < 64; ++d) a += sh[w][d] * sWc[d * 40 + f];
        if (alive) out[(size_t)i * 40 + f] += a;
    }
}

// ---------------------------------------------------------------------------
extern "C" void kernel_launch(void* const* d_in, const int* in_sizes, int n_in,
                              void* d_out, int out_size, void* d_ws, size_t ws_size,
                              hipStream_t stream) {
    const float* x     = (const float*)d_in[0];
    const int*   ei    = (const int*)d_in[1];   // [2,E] int32
    const float* Wego  = (const float*)d_in[2];
    const float* bego  = (const float*)d_in[3];
    const float* Wconv = (const float*)d_in[4]; // [2,64,64]
    const float* bconv = (const float*)d_in[5]; // [2,64]
    const float* Wcls  = (const float*)d_in[6]; // [192,40]
    const float* bcls  = (const float*)d_in[7];
    float* out = (float*)d_out;

    const int N = in_sizes[0] / 64;
    const int E = in_sizes[1] / 2;
    const int nb = cdiv(N, 256);                // scan blocks (<=512)

    // workspace layout (4-byte units):
    //   hws1[N*64] f | hws2[N*64] f | dis[N] f | cnt[N] i | indptr[N+1] i |
    //   cursor[N] i | partial[512] i | rows[E] i
    float* ws    = (float*)d_ws;
    float* hws1  = ws;
    float* hws2  = hws1 + (size_t)N * 64;
    float* dis   = hws2 + (size_t)N * 64;
    int*   cnt     = (int*)(dis + N);
    int*   indptr  = cnt + N;
    int*   cursor  = indptr + (N + 1);
    int*   partial = cursor + N;
    int*   rows    = partial + 512;

    hipMemsetAsync(cnt, 0, sizeof(int) * (size_t)N, stream);

    // ---- CSR build (counting sort by destination) ----
    k_hist<<<cdiv(E, 256), 256, 0, stream>>>(ei, cnt, E);
    k_scan1<<<nb, 256, 0, stream>>>(cnt, partial, N);
    k_scan2<<<1, 512, 0, stream>>>(partial, nb);
    k_scan3<<<nb, 256, 0, stream>>>(cnt, partial, indptr, cursor, dis, N);
    k_reorder<<<cdiv(E, 256), 256, 0, stream>>>(ei, cursor, rows, E);

    // ---- hop 0 (ego) + hws1 = dis * (x @ Wconv[0]) ----
    k_input<<<cdiv(N, 256), 256, 0, stream>>>(x, dis, Wego, bego, Wconv, Wcls, bcls,
                                              hws1, out, N);

    // ---- hop 1: gather hws1 -> h1 ; out += h1@Wcls1 ; hws2 = dis*(h1@Wconv1) ----
    k_hop<false><<<cdiv(N, 8), 512, 0, stream>>>(indptr, rows, dis, bconv,
                                                 Wconv + 64 * 64, Wcls + 64 * 40,
                                                 hws1, hws2, out, N);
    // ---- hop 2: gather hws2 -> h2 ; out += h2@Wcls2 ----
    k_hop<true><<<cdiv(N, 8), 512, 0, stream>>>(indptr, rows, dis, bconv + 64,
                                                Wconv, Wcls + 2 * 64 * 40,
                                                hws2, nullptr, out, N);
}

// Round 3
// 408.398 us; speedup vs baseline: 2.0037x; 1.4370x over previous
//
#include <hip/hip_runtime.h>

static inline int cdiv(long long a, long long b) { return (int)((a + b - 1) / b); }

// ---------------------------------------------------------------------------
// Histogram of destination nodes: cnt[c]++ per edge.
__global__ __launch_bounds__(256) void k_hist(const int* __restrict__ ei,
                                              int* __restrict__ cnt, int E) {
    int e = blockIdx.x * 256 + threadIdx.x;
    if (e < E) atomicAdd(&cnt[ei[E + e]], 1);
}

// Per-block sums of cnt -> partial[b]
__global__ __launch_bounds__(256) void k_scan1(const int* __restrict__ cnt,
                                               int* __restrict__ partial, int N) {
    __shared__ int s[256];
    int i = blockIdx.x * 256 + threadIdx.x;
    s[threadIdx.x] = (i < N) ? cnt[i] : 0;
    __syncthreads();
    for (int st = 128; st > 0; st >>= 1) {
        if (threadIdx.x < st) s[threadIdx.x] += s[threadIdx.x + st];
        __syncthreads();
    }
    if (threadIdx.x == 0) partial[blockIdx.x] = s[0];
}

// Exclusive scan of nb (<=512) partials, single block of 512.
__global__ __launch_bounds__(512) void k_scan2(int* __restrict__ partial, int nb) {
    __shared__ int s[512];
    int t = threadIdx.x;
    int v = (t < nb) ? partial[t] : 0;
    s[t] = v;
    __syncthreads();
    for (int st = 1; st < 512; st <<= 1) {
        int add = (t >= st) ? s[t - st] : 0;
        __syncthreads();
        s[t] += add;
        __syncthreads();
    }
    if (t < nb) partial[t] = s[t] - v;  // exclusive
}

// indptr/cursor from block-local exclusive scan + block offset; dis = rsqrt(deg+1).
__global__ __launch_bounds__(256) void k_scan3(const int* __restrict__ cnt,
                                               const int* __restrict__ partial,
                                               int* __restrict__ indptr,
                                               int* __restrict__ cursor,
                                               float* __restrict__ dis, int N) {
    __shared__ int s[256];
    int i = blockIdx.x * 256 + threadIdx.x;
    int v = (i < N) ? cnt[i] : 0;
    s[threadIdx.x] = v;
    __syncthreads();
    for (int st = 1; st < 256; st <<= 1) {
        int add = (threadIdx.x >= st) ? s[threadIdx.x - st] : 0;
        __syncthreads();
        s[threadIdx.x] += add;
        __syncthreads();
    }
    if (i < N) {
        int excl = partial[blockIdx.x] + s[threadIdx.x] - v;
        indptr[i] = excl;
        cursor[i] = excl;
        dis[i] = rsqrtf((float)v + 1.0f);   // self-loop adds 1
        if (i == N - 1) indptr[N] = excl + v;  // == E
    }
}

// Fill CSR rows via atomic cursors (order within a segment is arbitrary).
__global__ __launch_bounds__(256) void k_reorder(const int* __restrict__ ei,
                                                 int* __restrict__ cursor,
                                                 int* __restrict__ rows, int E) {
    int e = blockIdx.x * 256 + threadIdx.x;
    if (e < E) {
        int r = ei[e];
        int c = ei[E + e];
        int pos = atomicAdd(&cursor[c], 1);
        rows[pos] = r;
    }
}

// ---------------------------------------------------------------------------
// Per node i: hws1 = dis[i] * (x_i @ Wconv0); out_i = b_cls + relu(x_i@W_ego+b_ego)@Wcls0
__global__ __launch_bounds__(256) void k_input(const float* __restrict__ x,
                                               const float* __restrict__ dis,
                                               const float* __restrict__ Wego,
                                               const float* __restrict__ bego,
                                               const float* __restrict__ Wconv0,
                                               const float* __restrict__ Wcls0,
                                               const float* __restrict__ bcls,
                                               float* __restrict__ hws,
                                               float* __restrict__ out, int N) {
    __shared__ float sWe[64 * 64];
    __shared__ float sWc[64 * 64];
    __shared__ float sWcls[64 * 40];
    __shared__ float sbe[64];
    __shared__ float sbc[40];
    for (int t = threadIdx.x; t < 64 * 64; t += 256) { sWe[t] = Wego[t]; sWc[t] = Wconv0[t]; }
    for (int t = threadIdx.x; t < 64 * 40; t += 256) sWcls[t] = Wcls0[t];
    if (threadIdx.x < 64) sbe[threadIdx.x] = bego[threadIdx.x];
    if (threadIdx.x < 40) sbc[threadIdx.x] = bcls[threadIdx.x];
    __syncthreads();

    int i = blockIdx.x * 256 + threadIdx.x;
    if (i >= N) return;

    float xr[64];
    const float4* xp = (const float4*)(x + (size_t)i * 64);
#pragma unroll
    for (int d4 = 0; d4 < 16; ++d4) {
        float4 v = xp[d4];
        xr[d4 * 4 + 0] = v.x; xr[d4 * 4 + 1] = v.y;
        xr[d4 * 4 + 2] = v.z; xr[d4 * 4 + 3] = v.w;
    }

    float dsi = dis[i];
    float4* hwp = (float4*)(hws + (size_t)i * 64);
    for (int c4 = 0; c4 < 16; ++c4) {
        float4 acc = {0.f, 0.f, 0.f, 0.f};
#pragma unroll
        for (int d = 0; d < 64; ++d) {
            float xd = xr[d];
            const float4 w = *(const float4*)&sWc[d * 64 + c4 * 4];
            acc.x += xd * w.x; acc.y += xd * w.y;
            acc.z += xd * w.z; acc.w += xd * w.w;
        }
        acc.x *= dsi; acc.y *= dsi; acc.z *= dsi; acc.w *= dsi;
        hwp[c4] = acc;
    }

    float oacc[40];
#pragma unroll
    for (int j = 0; j < 40; ++j) oacc[j] = sbc[j];
    for (int c = 0; c < 64; ++c) {
        float acc = sbe[c];
#pragma unroll
        for (int d = 0; d < 64; ++d) acc += xr[d] * sWe[d * 64 + c];
        acc = fmaxf(acc, 0.0f);
#pragma unroll
        for (int j = 0; j < 40; ++j) oacc[j] += acc * sWcls[c * 40 + j];
    }
    float* op = out + (size_t)i * 40;
#pragma unroll
    for (int j = 0; j < 40; ++j) op[j] = oacc[j];
}

// ---------------------------------------------------------------------------
// Fused hop: one wave per node (8 nodes / 512-thread block), lane f = feature.
// Edge gather manually unrolled 8x/4x for memory-level parallelism.
template <bool LAST>
__global__ __launch_bounds__(512) void k_hop(const int* __restrict__ indptr,
                                             const int* __restrict__ rows,
                                             const float* __restrict__ dis,
                                             const float* __restrict__ bconv,
                                             const float* __restrict__ Wnext,
                                             const float* __restrict__ WclsPart,
                                             const float* __restrict__ hws_in,
                                             float* __restrict__ hws_out,
                                             float* __restrict__ out, int N) {
    __shared__ float sWn[64 * 64];
    __shared__ float sWc[64 * 40];
    __shared__ float sb[64];
    __shared__ float sh[8][64];
    if (!LAST)
        for (int t = threadIdx.x; t < 64 * 64; t += 512) sWn[t] = Wnext[t];
    for (int t = threadIdx.x; t < 64 * 40; t += 512) sWc[t] = WclsPart[t];
    if (threadIdx.x < 64) sb[threadIdx.x] = bconv[threadIdx.x];
    __syncthreads();

    const int w = threadIdx.x >> 6;
    const int f = threadIdx.x & 63;
    const int i = blockIdx.x * 8 + w;
    const bool alive = (i < N);

    float h = 0.0f;
    float dsi = 0.0f;
    if (alive) {
        dsi = dis[i];
        float acc = hws_in[(size_t)i * 64 + f];   // self-loop term
        // wave-uniform segment bounds -> scalar loads for rows[]
        int p0 = __builtin_amdgcn_readfirstlane(indptr[i]);
        int p1 = __builtin_amdgcn_readfirstlane(indptr[i + 1]);
        int p = p0;
        for (; p + 8 <= p1; p += 8) {
            int r0 = rows[p + 0], r1 = rows[p + 1], r2 = rows[p + 2], r3 = rows[p + 3];
            int r4 = rows[p + 4], r5 = rows[p + 5], r6 = rows[p + 6], r7 = rows[p + 7];
            float v0 = hws_in[(size_t)r0 * 64 + f];
            float v1 = hws_in[(size_t)r1 * 64 + f];
            float v2 = hws_in[(size_t)r2 * 64 + f];
            float v3 = hws_in[(size_t)r3 * 64 + f];
            float v4 = hws_in[(size_t)r4 * 64 + f];
            float v5 = hws_in[(size_t)r5 * 64 + f];
            float v6 = hws_in[(size_t)r6 * 64 + f];
            float v7 = hws_in[(size_t)r7 * 64 + f];
            acc += ((v0 + v1) + (v2 + v3)) + ((v4 + v5) + (v6 + v7));
        }
        for (; p + 4 <= p1; p += 4) {
            int r0 = rows[p + 0], r1 = rows[p + 1], r2 = rows[p + 2], r3 = rows[p + 3];
            float v0 = hws_in[(size_t)r0 * 64 + f];
            float v1 = hws_in[(size_t)r1 * 64 + f];
            float v2 = hws_in[(size_t)r2 * 64 + f];
            float v3 = hws_in[(size_t)r3 * 64 + f];
            acc += (v0 + v1) + (v2 + v3);
        }
        for (; p < p1; ++p) acc += hws_in[(size_t)rows[p] * 64 + f];
        h = fmaxf(fmaf(dsi, acc, sb[f]), 0.0f);
    }
    sh[w][f] = h;
    __syncthreads();

    if (!LAST) {
        float a = 0.0f;
#pragma unroll
        for (int d = 0; d < 64; ++d) a += sh[w][d] * sWn[d * 64 + f];
        if (alive) hws_out[(size_t)i * 64 + f] = dsi * a;
    }
    if (f < 40) {
        float a = 0.0f;
#pragma unroll
        for (int d = 0; d < 64; ++d) a += sh[w][d] * sWc[d * 40 + f];
        if (alive) out[(size_t)i * 40 + f] += a;
    }
}

// ---------------------------------------------------------------------------
extern "C" void kernel_launch(void* const* d_in, const int* in_sizes, int n_in,
                              void* d_out, int out_size, void* d_ws, size_t ws_size,
                              hipStream_t stream) {
    const float* x     = (const float*)d_in[0];
    const int*   ei    = (const int*)d_in[1];   // [2,E] int32
    const float* Wego  = (const float*)d_in[2];
    const float* bego  = (const float*)d_in[3];
    const float* Wconv = (const float*)d_in[4]; // [2,64,64]
    const float* bconv = (const float*)d_in[5]; // [2,64]
    const float* Wcls  = (const float*)d_in[6]; // [192,40]
    const float* bcls  = (const float*)d_in[7];
    float* out = (float*)d_out;

    const int N = in_sizes[0] / 64;
    const int E = in_sizes[1] / 2;
    const int nb = cdiv(N, 256);                // scan blocks (<=512)

    // workspace layout (4-byte units):
    //   hws1[N*64] f | hws2[N*64] f | dis[N] f | cnt[N] i | indptr[N+1] i |
    //   cursor[N] i | partial[512] i | rows[E] i
    float* ws    = (float*)d_ws;
    float* hws1  = ws;
    float* hws2  = hws1 + (size_t)N * 64;
    float* dis   = hws2 + (size_t)N * 64;
    int*   cnt     = (int*)(dis + N);
    int*   indptr  = cnt + N;
    int*   cursor  = indptr + (N + 1);
    int*   partial = cursor + N;
    int*   rows    = partial + 512;

    hipMemsetAsync(cnt, 0, sizeof(int) * (size_t)N, stream);

    // ---- CSR build (counting sort by destination) ----
    k_hist<<<cdiv(E, 256), 256, 0, stream>>>(ei, cnt, E);
    k_scan1<<<nb, 256, 0, stream>>>(cnt, partial, N);
    k_scan2<<<1, 512, 0, stream>>>(partial, nb);
    k_scan3<<<nb, 256, 0, stream>>>(cnt, partial, indptr, cursor, dis, N);
    k_reorder<<<cdiv(E, 256), 256, 0, stream>>>(ei, cursor, rows, E);

    // ---- hop 0 (ego) + hws1 = dis * (x @ Wconv[0]) ----
    k_input<<<cdiv(N, 256), 256, 0, stream>>>(x, dis, Wego, bego, Wconv, Wcls, bcls,
                                              hws1, out, N);

    // ---- hop 1: gather hws1 -> h1 ; out += h1@Wcls1 ; hws2 = dis*(h1@Wconv1) ----
    k_hop<false><<<cdiv(N, 8), 512, 0, stream>>>(indptr, rows, dis, bconv,
                                                 Wconv + 64 * 64, Wcls + 64 * 40,
                                                 hws1, hws2, out, N);
    // ---- hop 2: gather hws2 -> h2 ; out += h2@Wcls2 ----
    k_hop<true><<<cdiv(N, 8), 512, 0, stream>>>(indptr, rows, dis, bconv + 64,
                                                Wconv, Wcls + 2 * 64 * 40,
                                                hws2, nullptr, out, N);
}

// Round 4
// 405.368 us; speedup vs baseline: 2.0186x; 1.0075x over previous
//
#include <hip/hip_runtime.h>

using u16 = unsigned short;
using u32 = unsigned int;

static inline int cdiv(long long a, long long b) { return (int)((a + b - 1) / b); }

__device__ __forceinline__ u16 f2bf(float x) {
    u32 u = __builtin_bit_cast(u32, x);
    u += 0x7fffu + ((u >> 16) & 1u);   // RTNE
    return (u16)(u >> 16);
}
__device__ __forceinline__ float bf2f(u16 h) {
    u32 u = ((u32)h) << 16;
    return __builtin_bit_cast(float, u);
}

// ---------------------------------------------------------------------------
__global__ __launch_bounds__(256) void k_hist(const int* __restrict__ ei,
                                              int* __restrict__ cnt, int E) {
    int e = blockIdx.x * 256 + threadIdx.x;
    if (e < E) atomicAdd(&cnt[ei[E + e]], 1);
}

// Per-block sums of cnt -> partial[b]
__global__ __launch_bounds__(256) void k_scan1(const int* __restrict__ cnt,
                                               int* __restrict__ partial, int N) {
    __shared__ int s[256];
    int i = blockIdx.x * 256 + threadIdx.x;
    s[threadIdx.x] = (i < N) ? cnt[i] : 0;
    __syncthreads();
    for (int st = 128; st > 0; st >>= 1) {
        if (threadIdx.x < st) s[threadIdx.x] += s[threadIdx.x + st];
        __syncthreads();
    }
    if (threadIdx.x == 0) partial[blockIdx.x] = s[0];
}

// Fused: indptr/cursor (counting-sort scan, block prefix computed in-kernel),
// dis = rsqrt(deg+1), hws1 = bf16(dis * x@Wconv0),
// out = b_cls + relu(x@Wego+b_ego)@Wcls0.
__global__ __launch_bounds__(256) void k_scan_input(const int* __restrict__ cnt,
                                                    const int* __restrict__ partial,
                                                    int* __restrict__ indptr,
                                                    int* __restrict__ cursor,
                                                    float* __restrict__ dis,
                                                    const float* __restrict__ x,
                                                    const float* __restrict__ Wego,
                                                    const float* __restrict__ bego,
                                                    const float* __restrict__ Wconv0,
                                                    const float* __restrict__ Wcls0,
                                                    const float* __restrict__ bcls,
                                                    u16* __restrict__ hws,
                                                    float* __restrict__ out, int N) {
    __shared__ int s[256];
    __shared__ int s_off;
    __shared__ float sWe[64 * 64];
    __shared__ float sWc[64 * 64];
    __shared__ float sWcls[64 * 40];
    __shared__ float sbe[64];
    __shared__ float sbc[40];
    for (int t = threadIdx.x; t < 64 * 64; t += 256) { sWe[t] = Wego[t]; sWc[t] = Wconv0[t]; }
    for (int t = threadIdx.x; t < 64 * 40; t += 256) sWcls[t] = Wcls0[t];
    if (threadIdx.x < 64) sbe[threadIdx.x] = bego[threadIdx.x];
    if (threadIdx.x < 40) sbc[threadIdx.x] = bcls[threadIdx.x];

    // ---- prefix of partial[0..blockIdx) ----
    int ap = 0;
    for (int j = threadIdx.x; j < blockIdx.x; j += 256) ap += partial[j];
    s[threadIdx.x] = ap;
    __syncthreads();
    for (int st = 128; st > 0; st >>= 1) {
        if (threadIdx.x < st) s[threadIdx.x] += s[threadIdx.x + st];
        __syncthreads();
    }
    if (threadIdx.x == 0) s_off = s[0];
    __syncthreads();
    const int block_off = s_off;
    __syncthreads();

    // ---- in-block inclusive scan of cnt ----
    const int i = blockIdx.x * 256 + threadIdx.x;
    const bool alive = (i < N);
    int v = alive ? cnt[i] : 0;
    s[threadIdx.x] = v;
    __syncthreads();
    for (int st = 1; st < 256; st <<= 1) {
        int add = (threadIdx.x >= st) ? s[threadIdx.x - st] : 0;
        __syncthreads();
        s[threadIdx.x] += add;
        __syncthreads();
    }
    const float dsi = rsqrtf((float)v + 1.0f);   // self-loop adds 1
    if (alive) {
        int excl = block_off + s[threadIdx.x] - v;
        indptr[i] = excl;
        cursor[i] = excl;
        dis[i] = dsi;
        if (i == N - 1) indptr[N] = excl + v;    // == E
    }

    // ---- k_input body ----
    float xr[64];
    if (alive) {
        const float4* xp = (const float4*)(x + (size_t)i * 64);
#pragma unroll
        for (int d4 = 0; d4 < 16; ++d4) {
            float4 vv = xp[d4];
            xr[d4 * 4 + 0] = vv.x; xr[d4 * 4 + 1] = vv.y;
            xr[d4 * 4 + 2] = vv.z; xr[d4 * 4 + 3] = vv.w;
        }
    } else {
#pragma unroll
        for (int d = 0; d < 64; ++d) xr[d] = 0.f;
    }

    u32* hwp = (u32*)(hws + (size_t)i * 64);     // 64 bf16 = 32 u32 per row
    for (int c4 = 0; c4 < 16; ++c4) {
        float4 acc = {0.f, 0.f, 0.f, 0.f};
#pragma unroll
        for (int d = 0; d < 64; ++d) {
            float xd = xr[d];
            const float4 w = *(const float4*)&sWc[d * 64 + c4 * 4];
            acc.x += xd * w.x; acc.y += xd * w.y;
            acc.z += xd * w.z; acc.w += xd * w.w;
        }
        if (alive) {
            hwp[c4 * 2 + 0] = (u32)f2bf(dsi * acc.x) | ((u32)f2bf(dsi * acc.y) << 16);
            hwp[c4 * 2 + 1] = (u32)f2bf(dsi * acc.z) | ((u32)f2bf(dsi * acc.w) << 16);
        }
    }

    float oacc[40];
#pragma unroll
    for (int j = 0; j < 40; ++j) oacc[j] = sbc[j];
    for (int c = 0; c < 64; ++c) {
        float acc = sbe[c];
#pragma unroll
        for (int d = 0; d < 64; ++d) acc += xr[d] * sWe[d * 64 + c];
        acc = fmaxf(acc, 0.0f);
#pragma unroll
        for (int j = 0; j < 40; ++j) oacc[j] += acc * sWcls[c * 40 + j];
    }
    if (alive) {
        float* op = out + (size_t)i * 40;
#pragma unroll
        for (int j = 0; j < 40; ++j) op[j] = oacc[j];
    }
}

// Fill CSR rows via atomic cursors (order within a segment is arbitrary).
__global__ __launch_bounds__(256) void k_reorder(const int* __restrict__ ei,
                                                 int* __restrict__ cursor,
                                                 int* __restrict__ rows, int E) {
    int e = blockIdx.x * 256 + threadIdx.x;
    if (e < E) {
        int r = ei[e];
        int c = ei[E + e];
        int pos = atomicAdd(&cursor[c], 1);
        rows[pos] = r;
    }
}

// ---------------------------------------------------------------------------
// Fused hop: one wave per node, lane f = feature. bf16 gather (128B rows),
// fp32 accumulate, 8x/4x MLP unroll.
template <bool LAST>
__global__ __launch_bounds__(512) void k_hop(const int* __restrict__ indptr,
                                             const int* __restrict__ rows,
                                             const float* __restrict__ dis,
                                             const float* __restrict__ bconv,
                                             const float* __restrict__ Wnext,
                                             const float* __restrict__ WclsPart,
                                             const u16* __restrict__ hws_in,
                                             u16* __restrict__ hws_out,
                                             float* __restrict__ out, int N) {
    __shared__ float sWn[64 * 64];
    __shared__ float sWc[64 * 40];
    __shared__ float sb[64];
    __shared__ float sh[8][64];
    if (!LAST)
        for (int t = threadIdx.x; t < 64 * 64; t += 512) sWn[t] = Wnext[t];
    for (int t = threadIdx.x; t < 64 * 40; t += 512) sWc[t] = WclsPart[t];
    if (threadIdx.x < 64) sb[threadIdx.x] = bconv[threadIdx.x];
    __syncthreads();

    const int w = threadIdx.x >> 6;
    const int f = threadIdx.x & 63;
    const int i = blockIdx.x * 8 + w;
    const bool alive = (i < N);

    float h = 0.0f;
    float dsi = 0.0f;
    if (alive) {
        dsi = dis[i];
        float acc = bf2f(hws_in[(size_t)i * 64 + f]);   // self-loop term
        int p0 = __builtin_amdgcn_readfirstlane(indptr[i]);
        int p1 = __builtin_amdgcn_readfirstlane(indptr[i + 1]);
        int p = p0;
        for (; p + 8 <= p1; p += 8) {
            int r0 = rows[p + 0], r1 = rows[p + 1], r2 = rows[p + 2], r3 = rows[p + 3];
            int r4 = rows[p + 4], r5 = rows[p + 5], r6 = rows[p + 6], r7 = rows[p + 7];
            u16 v0 = hws_in[(size_t)r0 * 64 + f];
            u16 v1 = hws_in[(size_t)r1 * 64 + f];
            u16 v2 = hws_in[(size_t)r2 * 64 + f];
            u16 v3 = hws_in[(size_t)r3 * 64 + f];
            u16 v4 = hws_in[(size_t)r4 * 64 + f];
            u16 v5 = hws_in[(size_t)r5 * 64 + f];
            u16 v6 = hws_in[(size_t)r6 * 64 + f];
            u16 v7 = hws_in[(size_t)r7 * 64 + f];
            acc += ((bf2f(v0) + bf2f(v1)) + (bf2f(v2) + bf2f(v3))) +
                   ((bf2f(v4) + bf2f(v5)) + (bf2f(v6) + bf2f(v7)));
        }
        for (; p + 4 <= p1; p += 4) {
            int r0 = rows[p + 0], r1 = rows[p + 1], r2 = rows[p + 2], r3 = rows[p + 3];
            u16 v0 = hws_in[(size_t)r0 * 64 + f];
            u16 v1 = hws_in[(size_t)r1 * 64 + f];
            u16 v2 = hws_in[(size_t)r2 * 64 + f];
            u16 v3 = hws_in[(size_t)r3 * 64 + f];
            acc += (bf2f(v0) + bf2f(v1)) + (bf2f(v2) + bf2f(v3));
        }
        for (; p < p1; ++p) acc += bf2f(hws_in[(size_t)rows[p] * 64 + f]);
        h = fmaxf(fmaf(dsi, acc, sb[f]), 0.0f);
    }
    sh[w][f] = h;
    __syncthreads();

    if (!LAST) {
        float a = 0.0f;
#pragma unroll
        for (int d = 0; d < 64; ++d) a += sh[w][d] * sWn[d * 64 + f];
        if (alive) hws_out[(size_t)i * 64 + f] = f2bf(dsi * a);
    }
    if (f < 40) {
        float a = 0.0f;
#pragma unroll
        for (int d = 0; d < 64; ++d) a += sh[w][d] * sWc[d * 40 + f];
        if (alive) out[(size_t)i * 40 + f] += a;
    }
}

// ---------------------------------------------------------------------------
extern "C" void kernel_launch(void* const* d_in, const int* in_sizes, int n_in,
                              void* d_out, int out_size, void* d_ws, size_t ws_size,
                              hipStream_t stream) {
    const float* x     = (const float*)d_in[0];
    const int*   ei    = (const int*)d_in[1];   // [2,E] int32
    const float* Wego  = (const float*)d_in[2];
    const float* bego  = (const float*)d_in[3];
    const float* Wconv = (const float*)d_in[4]; // [2,64,64]
    const float* bconv = (const float*)d_in[5]; // [2,64]
    const float* Wcls  = (const float*)d_in[6]; // [192,40]
    const float* bcls  = (const float*)d_in[7];
    float* out = (float*)d_out;

    const int N = in_sizes[0] / 64;
    const int E = in_sizes[1] / 2;
    const int nb = cdiv(N, 256);

    // workspace layout (bytes):
    //  hws1 u16[N*64] | hws2 u16[N*64] | dis f[N] | cnt i[N] | indptr i[N+1] |
    //  cursor i[N] | partial i[512] | rows i[E]
    u16* hws1 = (u16*)d_ws;
    u16* hws2 = hws1 + (size_t)N * 64;
    float* dis = (float*)(hws2 + (size_t)N * 64);
    int* cnt     = (int*)(dis + N);
    int* indptr  = cnt + N;
    int* cursor  = indptr + (N + 1);
    int* partial = cursor + N;
    int* rows    = partial + 512;

    hipMemsetAsync(cnt, 0, sizeof(int) * (size_t)N, stream);

    // ---- CSR build + fused input ----
    k_hist<<<cdiv(E, 256), 256, 0, stream>>>(ei, cnt, E);
    k_scan1<<<nb, 256, 0, stream>>>(cnt, partial, N);
    k_scan_input<<<nb, 256, 0, stream>>>(cnt, partial, indptr, cursor, dis,
                                         x, Wego, bego, Wconv, Wcls, bcls,
                                         hws1, out, N);
    k_reorder<<<cdiv(E, 256), 256, 0, stream>>>(ei, cursor, rows, E);

    // ---- hop 1 ----
    k_hop<false><<<cdiv(N, 8), 512, 0, stream>>>(indptr, rows, dis, bconv,
                                                 Wconv + 64 * 64, Wcls + 64 * 40,
                                                 hws1, hws2, out, N);
    // ---- hop 2 ----
    k_hop<true><<<cdiv(N, 8), 512, 0, stream>>>(indptr, rows, dis, bconv + 64,
                                                Wconv, Wcls + 2 * 64 * 40,
                                                hws2, nullptr, out, N);
}